// Round 7
// baseline (1075.472 us; speedup 1.0000x reference)
//
#include <hip/hip_runtime.h>
#include <type_traits>

// ---------------------------------------------------------------------------
// CSAAttention — round 7 (= round 6 with compile fix: split2 by value).
//   Selection path (Q, K, Kc fp64-acc -> fp32 store; kn/dots fp64; exact
//   radix top-64): UNCHANGED from round 5 (bit-identical selection sets).
//   Value path (V, Vc, Wo): bf16 2-term-split MFMA GEMM (3 passes).
// ---------------------------------------------------------------------------

#define DEVI __device__ __forceinline__

constexpr int Tn = 1024;
constexpr int Cn = 1024;
constexpr int Hn = 16;

typedef short bf16x8 __attribute__((ext_vector_type(8)));
typedef short short4v __attribute__((ext_vector_type(4)));
typedef float f32x4 __attribute__((ext_vector_type(4)));

DEVI int wsumi(int v)   { for (int m = 1; m < 64; m <<= 1) v += __shfl_xor(v, m); return v; }
DEVI int wmini(int v)   { for (int m = 1; m < 64; m <<= 1) { int o = __shfl_xor(v, m); v = o < v ? o : v; } return v; }
DEVI float wfmax(float v){ for (int m = 1; m < 64; m <<= 1) v = fmaxf(v, __shfl_xor(v, m)); return v; }
DEVI float wfsum(float v){ for (int m = 1; m < 64; m <<= 1) v += __shfl_xor(v, m); return v; }

DEVI unsigned long long mapd(double x) {  // monotone fp64 -> uint64
  unsigned long long b = (unsigned long long)__double_as_longlong(x);
  return (b >> 63) ? ~b : (b | 0x8000000000000000ull);
}

DEVI unsigned short f2bf_rne(float x) {
  unsigned u = __float_as_uint(x);
  u += 0x7fffu + ((u >> 16) & 1u);
  return (unsigned short)(u >> 16);
}
struct BfPair { short hi, lo; };
DEVI BfPair split2(float x) {
  unsigned short h = f2bf_rne(x);
  float hf = __uint_as_float(((unsigned)h) << 16);
  BfPair r;
  r.hi = (short)h;
  r.lo = (short)f2bf_rne(x - hf);
  return r;
}

// ---------------------------------------------------------------------------
// Value-path MFMA GEMM (bf16 split, 3 passes). C = A * op(B) + bias, fp32 out.
// Tile 128x128, 256 thr (4 waves), wave tile 64x64, BK=32.
// LDS layout: 16B blocks [kgran(4)][row(128)] of 8 bf16 — conflict-free
// ds_read_b128 fragments. BTRANS: B[N][K] (C=A*B^T); else B[K][N] (Vc).
// BIASMODE: 1 bias[n], 2 bias[m]. Z-batch via zB/zC element strides.
// ---------------------------------------------------------------------------
template <bool BTRANS, int BIASMODE>
__global__ __launch_bounds__(256) void mfma_gemm_k(
    const float* __restrict__ A, const float* __restrict__ B,
    const float* __restrict__ bias, float* __restrict__ C,
    int Kd, int lda, int ldb, int ldc, long long zB, long long zC)
{
  __shared__ short Ah[4 * 128 * 8];
  __shared__ short Al[4 * 128 * 8];
  __shared__ short Bh[4 * 128 * 8];
  __shared__ short Bl[4 * 128 * 8];

  const float* Bz = B + (size_t)blockIdx.z * (size_t)zB;
  float* Cz = C + (size_t)blockIdx.z * (size_t)zC;

  const int tid = threadIdx.x;
  const int lane = tid & 63, w = tid >> 6;
  const int wr = w >> 1, wc = w & 1;
  const int m0 = blockIdx.y * 128, n0 = blockIdx.x * 128;

  f32x4 acc[4][4];
#pragma unroll
  for (int i = 0; i < 4; ++i)
#pragma unroll
    for (int j = 0; j < 4; ++j) acc[i][j] = (f32x4){0.f, 0.f, 0.f, 0.f};

  const int srow = tid & 127;        // staging row (m or n)
  const int skseg = tid >> 7;        // 0/1 -> k halves

  for (int k0 = 0; k0 < Kd; k0 += 32) {
    // ---- stage A: rows m0+srow, k = k0 + skseg*16 + [0,16)
#pragma unroll
    for (int i = 0; i < 4; ++i) {
      int kl = skseg * 16 + i * 4;
      float4 a = *(const float4*)(A + (size_t)(m0 + srow) * lda + k0 + kl);
      BfPair p0 = split2(a.x), p1 = split2(a.y), p2 = split2(a.z), p3 = split2(a.w);
      short4v h = {p0.hi, p1.hi, p2.hi, p3.hi};
      short4v l = {p0.lo, p1.lo, p2.lo, p3.lo};
      int idx = (((kl >> 3) * 128) + srow) * 8 + (kl & 7);
      *(short4v*)&Ah[idx] = h;
      *(short4v*)&Al[idx] = l;
    }
    // ---- stage B
    if (BTRANS) {  // B[N][K] row-major: same pattern as A with n-rows
#pragma unroll
      for (int i = 0; i < 4; ++i) {
        int kl = skseg * 16 + i * 4;
        float4 b = *(const float4*)(Bz + (size_t)(n0 + srow) * ldb + k0 + kl);
        BfPair p0 = split2(b.x), p1 = split2(b.y), p2 = split2(b.z), p3 = split2(b.w);
        short4v h = {p0.hi, p1.hi, p2.hi, p3.hi};
        short4v l = {p0.lo, p1.lo, p2.lo, p3.lo};
        int idx = (((kl >> 3) * 128) + srow) * 8 + (kl & 7);
        *(short4v*)&Bh[idx] = h;
        *(short4v*)&Bl[idx] = l;
      }
    } else {       // B[K][N]: thread owns column n0+srow, 16 consecutive k
      short hv[16], lv[16];
#pragma unroll
      for (int i = 0; i < 16; ++i) {
        int k = skseg * 16 + i;
        BfPair p = split2(Bz[(size_t)(k0 + k) * ldb + n0 + srow]);
        hv[i] = p.hi; lv[i] = p.lo;
      }
      int idx0 = ((skseg * 2) * 128 + srow) * 8;
      int idx1 = ((skseg * 2 + 1) * 128 + srow) * 8;
      bf16x8 h0 = {hv[0], hv[1], hv[2], hv[3], hv[4], hv[5], hv[6], hv[7]};
      bf16x8 h1 = {hv[8], hv[9], hv[10], hv[11], hv[12], hv[13], hv[14], hv[15]};
      bf16x8 l0 = {lv[0], lv[1], lv[2], lv[3], lv[4], lv[5], lv[6], lv[7]};
      bf16x8 l1 = {lv[8], lv[9], lv[10], lv[11], lv[12], lv[13], lv[14], lv[15]};
      *(bf16x8*)&Bh[idx0] = h0; *(bf16x8*)&Bh[idx1] = h1;
      *(bf16x8*)&Bl[idx0] = l0; *(bf16x8*)&Bl[idx1] = l1;
    }
    __syncthreads();

    // ---- fragments + MFMA
    const int kg = lane >> 4, r16 = lane & 15;
    bf16x8 ah[4], al[4], bh[4], bl[4];
#pragma unroll
    for (int f = 0; f < 4; ++f) {
      int ia = (kg * 128 + wr * 64 + f * 16 + r16) * 8;
      int ib = (kg * 128 + wc * 64 + f * 16 + r16) * 8;
      ah[f] = *(const bf16x8*)&Ah[ia];
      al[f] = *(const bf16x8*)&Al[ia];
      bh[f] = *(const bf16x8*)&Bh[ib];
      bl[f] = *(const bf16x8*)&Bl[ib];
    }
#pragma unroll
    for (int fr = 0; fr < 4; ++fr)
#pragma unroll
      for (int fc = 0; fc < 4; ++fc) {
        f32x4 c = acc[fr][fc];
        c = __builtin_amdgcn_mfma_f32_16x16x32_bf16(al[fr], bh[fc], c, 0, 0, 0);
        c = __builtin_amdgcn_mfma_f32_16x16x32_bf16(ah[fr], bl[fc], c, 0, 0, 0);
        c = __builtin_amdgcn_mfma_f32_16x16x32_bf16(ah[fr], bh[fc], c, 0, 0, 0);
        acc[fr][fc] = c;
      }
    __syncthreads();
  }

  // ---- epilogue: C/D map col=lane&15, row=(lane>>4)*4+reg
  const int cg = lane >> 4, c16 = lane & 15;
#pragma unroll
  for (int fr = 0; fr < 4; ++fr)
#pragma unroll
    for (int fc = 0; fc < 4; ++fc) {
      int col = n0 + wc * 64 + fc * 16 + c16;
      float cb = (BIASMODE == 1) ? bias[col] : 0.f;
#pragma unroll
      for (int rr = 0; rr < 4; ++rr) {
        int row = m0 + wr * 64 + fr * 16 + cg * 4 + rr;
        float rb = (BIASMODE == 2) ? bias[row] : 0.f;
        Cz[(size_t)row * ldc + col] = acc[fr][fc][rr] + cb + rb;
      }
    }
}

// ---------------------------------------------------------------------------
// Selection-path tiled GEMM (UNCHANGED numerics from round 5).
// ---------------------------------------------------------------------------
template <typename OUTT, typename ACCT, bool BTRANS, int BIASMODE, bool SIM>
__global__ __launch_bounds__(256) void gemm_k(
    const float* __restrict__ A, const float* __restrict__ B,
    const float* __restrict__ bias, OUTT* __restrict__ C,
    int Kd, int lda, int ldb, int ldc,
    long long zA, long long zB, long long zC, int group_base)
{
  __shared__ float As[16][68];
  __shared__ float Bs[16][68];

  size_t offA, offB, offC;
  if (SIM) {
    int pair = group_base + (int)blockIdx.z;
    int bb = pair >> 4, hh = pair & 15;
    offA = ((size_t)bb * Tn) * (size_t)lda + (size_t)hh * 64;
    offB = ((size_t)bb * Cn) * (size_t)ldb + (size_t)hh * 64;
    offC = (size_t)blockIdx.z * (size_t)Tn * (size_t)ldc;
  } else {
    offA = (size_t)blockIdx.z * (size_t)zA;
    offB = (size_t)blockIdx.z * (size_t)zB;
    offC = (size_t)blockIdx.z * (size_t)zC;
  }
  const float* Ab = A + offA;
  const float* Bb = B + offB;
  OUTT* Cb = C + offC;

  const int tid = threadIdx.x;
  const int tx = tid & 15, ty = tid >> 4;
  const int m0 = blockIdx.y * 64, n0 = blockIdx.x * 64;

  ACCT acc[4][4];
#pragma unroll
  for (int i = 0; i < 4; ++i)
#pragma unroll
    for (int j = 0; j < 4; ++j) acc[i][j] = (ACCT)0;

  for (int k0 = 0; k0 < Kd; k0 += 16) {
    {
      int m = tid >> 2, kf = tid & 3;
      float4 a = *(const float4*)(Ab + (size_t)(m0 + m) * lda + k0 + 4 * kf);
      As[4 * kf + 0][m] = a.x; As[4 * kf + 1][m] = a.y;
      As[4 * kf + 2][m] = a.z; As[4 * kf + 3][m] = a.w;
    }
    if (BTRANS) {
      int n = tid >> 2, kf = tid & 3;
      float4 b = *(const float4*)(Bb + (size_t)(n0 + n) * ldb + k0 + 4 * kf);
      Bs[4 * kf + 0][n] = b.x; Bs[4 * kf + 1][n] = b.y;
      Bs[4 * kf + 2][n] = b.z; Bs[4 * kf + 3][n] = b.w;
    } else {
      int k = tid >> 4, nf = tid & 15;
      float4 b = *(const float4*)(Bb + (size_t)(k0 + k) * ldb + n0 + 4 * nf);
      *(float4*)&Bs[k][4 * nf] = b;
    }
    __syncthreads();
#pragma unroll
    for (int k = 0; k < 16; ++k) {
      float4 a4 = *(const float4*)&As[k][4 * ty];
      float4 b4 = *(const float4*)&Bs[k][4 * tx];
      float av[4] = {a4.x, a4.y, a4.z, a4.w};
      float bv[4] = {b4.x, b4.y, b4.z, b4.w};
#pragma unroll
      for (int i = 0; i < 4; ++i)
#pragma unroll
        for (int j = 0; j < 4; ++j)
          acc[i][j] += (ACCT)av[i] * (ACCT)bv[j];
    }
    __syncthreads();
  }

  if constexpr (std::is_same<OUTT, double>::value) {
#pragma unroll
    for (int i = 0; i < 4; ++i) {
      size_t m = (size_t)(m0 + 4 * ty + i);
      double* p = (double*)Cb + m * ldc + n0 + 4 * tx;
      p[0] = (double)acc[i][0]; p[1] = (double)acc[i][1];
      p[2] = (double)acc[i][2]; p[3] = (double)acc[i][3];
    }
  } else {
    float cbv[4] = {0.f, 0.f, 0.f, 0.f};
    if (BIASMODE == 1) {
      float4 b4 = *(const float4*)(bias + n0 + 4 * tx);
      cbv[0] = b4.x; cbv[1] = b4.y; cbv[2] = b4.z; cbv[3] = b4.w;
    }
#pragma unroll
    for (int i = 0; i < 4; ++i) {
      int m = m0 + 4 * ty + i;
      float rb = (BIASMODE == 2) ? bias[m] : 0.f;
      float4 s;
      s.x = (float)acc[i][0] + cbv[0] + rb;
      s.y = (float)acc[i][1] + cbv[1] + rb;
      s.z = (float)acc[i][2] + cbv[2] + rb;
      s.w = (float)acc[i][3] + cbv[3] + rb;
      *(float4*)((float*)Cb + (size_t)m * ldc + n0 + 4 * tx) = s;
    }
  }
}

// kn[b*16+h][c] = 1 / max(||Kc[b, c, h*64 : +64]||, 1e-12)   (fp64)
__global__ __launch_bounds__(256) void kn_k2(const float* __restrict__ Kc,
                                             double* __restrict__ kn)
{
  int idx = (int)blockIdx.x * 256 + (int)threadIdx.x;  // [0, 32768)
  int c = idx & 1023;
  int p = idx >> 10;
  int b = p >> 4, h = p & 15;
  const float* row = Kc + ((size_t)(b * 1024 + c)) * 1024 + h * 64;
  double s = 0.0;
  for (int d = 0; d < 64; ++d) { double v = (double)row[d]; s += v * v; }
  kn[(size_t)p * 1024 + c] = 1.0 / fmax(sqrt(s), 1e-12);
}

// Fused exact top-64 + softmax + PV (UNCHANGED from round 5).
__global__ __launch_bounds__(256) void topk_attn_k(
    const double* __restrict__ dotb, const double* __restrict__ kn,
    const float* __restrict__ Vc, float* __restrict__ attnout, int group_base)
{
  __shared__ int sC[4][64];
  __shared__ float sD[4][64];

  const int lane = threadIdx.x & 63, wv = threadIdx.x >> 6;
  const int g = (int)blockIdx.x >> 8;
  const int t = ((int)blockIdx.x & 255) * 4 + wv;
  const int pair = group_base + g;
  const int bb = pair >> 4, hh = pair & 15;

  const double* drow = dotb + ((size_t)g * Tn + t) * (size_t)Cn;
  const double* knr  = kn + ((size_t)(bb * Hn + hh)) * Cn;

  double dv[16];
  unsigned long long u[16];
#pragma unroll
  for (int j = 0; j < 8; ++j) {
    double2 dd = *(const double2*)(drow + j * 128 + 2 * lane);
    double2 kk = *(const double2*)(knr  + j * 128 + 2 * lane);
    dv[2 * j] = dd.x; dv[2 * j + 1] = dd.y;
    u[2 * j]     = mapd(dd.x * kk.x);
    u[2 * j + 1] = mapd(dd.y * kk.y);
  }
  unsigned hi[16];
#pragma unroll
  for (int i = 0; i < 16; ++i) hi[i] = (unsigned)(u[i] >> 32);

  unsigned TH = 0;
  for (int bit = 31; bit >= 0; --bit) {
    unsigned Tc = TH | (1u << bit);
    int c = 0;
#pragma unroll
    for (int i = 0; i < 16; ++i) c += (hi[i] >= Tc);
    if (wsumi(c) >= 64) TH = Tc;
  }
  int mhi = 0;
#pragma unroll
  for (int i = 0; i < 16; ++i) mhi += (hi[i] > TH);
  mhi = wsumi(mhi);
  const int need1 = 64 - mhi;
  unsigned TL = 0;
  for (int bit = 31; bit >= 0; --bit) {
    unsigned Tc = TL | (1u << bit);
    int c = 0;
#pragma unroll
    for (int i = 0; i < 16; ++i) c += (hi[i] == TH && (unsigned)u[i] >= Tc);
    if (wsumi(c) >= need1) TL = Tc;
  }
  const unsigned long long V64 = ((unsigned long long)TH << 32) | TL;

  int base = 0;
#pragma unroll
  for (int i = 0; i < 16; ++i) {
    const int cix = 128 * (i >> 1) + 2 * lane + (i & 1);
    bool sel = (u[i] > V64);
    unsigned long long mk = __ballot(sel);
    if (sel) {
      int r = __popcll(mk & ((1ull << lane) - 1ull));
      sC[wv][base + r] = cix;
      sD[wv][base + r] = (float)dv[i];
    }
    base += __popcll(mk);
  }
  const int need = 64 - base;
  unsigned taken = 0;
  for (int r = 0; r < need; ++r) {
    int mn = 0x7fffffff;
#pragma unroll
    for (int i = 0; i < 16; ++i) {
      int cix = 128 * (i >> 1) + 2 * lane + (i & 1);
      if (u[i] == V64 && !((taken >> i) & 1u)) mn = mn < cix ? mn : cix;
    }
    mn = wmini(mn);
#pragma unroll
    for (int i = 0; i < 16; ++i) {
      int cix = 128 * (i >> 1) + 2 * lane + (i & 1);
      if (u[i] == V64 && !((taken >> i) & 1u) && cix == mn) {
        taken |= 1u << i;
        sC[wv][base + r] = mn;
        sD[wv][base + r] = (float)dv[i];
      }
    }
  }
  __syncthreads();

  int ck = sC[wv][lane];
  float sc = sD[wv][lane] * 0.125f;
  float mx = wfmax(sc);
  float w = expf(sc - mx);
  float sw = wfsum(w);
  w /= sw;

  const float* Vb = Vc + (size_t)bb * ((size_t)Cn * 1024) + hh * 64 + lane;
  float acc = 0.f;
#pragma unroll 4
  for (int k = 0; k < 64; ++k) {
    int c = __shfl(ck, k);
    float wk = __shfl(w, k);
    acc = fmaf(wk, Vb[(size_t)c * 1024], acc);
  }
  attnout[((size_t)(bb * Tn + t)) * 1024 + hh * 64 + lane] = acc;
}

// ---------------------------------------------------------------------------
extern "C" void kernel_launch(void* const* d_in, const int* in_sizes, int n_in,
                              void* d_out, int out_size, void* d_ws, size_t ws_size,
                              hipStream_t stream)
{
  const float* x  = (const float*)d_in[0];
  const float* Wq = (const float*)d_in[1];
  const float* bq = (const float*)d_in[2];
  const float* Wk = (const float*)d_in[3];
  const float* bk = (const float*)d_in[4];
  const float* Wv = (const float*)d_in[5];
  const float* bv = (const float*)d_in[6];
  const float* Wo = (const float*)d_in[7];
  const float* bo = (const float*)d_in[8];
  const float* Wc = (const float*)d_in[9];
  const float* bc = (const float*)d_in[10];
  float* out = (float*)d_out;

  const size_t NE = (size_t)2048 * 1024;
  float* Q  = (float*)d_ws;
  float* Kf = Q + NE;
  float* Vf = Kf + NE;
  float* Kc = Vf + NE;
  float* Vc = Kc + NE;
  float* at = Vc + NE;
  double* kn = (double*)(at + NE);
  double* tail = kn + 32768;

  const size_t fixedB = 6 * NE * 4 + 32768 * 8;
  const size_t dotPairB = (size_t)Tn * Cn * 8;  // 8 MB per (b,h) pair
  if (ws_size < fixedB) return;

  size_t rem = ws_size - fixedB;
  double* dotp; int G;
  if      (rem >= 8 * dotPairB) { G = 8; dotp = tail; }
  else if (rem >= 4 * dotPairB) { G = 4; dotp = tail; }
  else if (rem >= 2 * dotPairB) { G = 2; dotp = tail; }
  else { G = 2; dotp = (double*)Kf; }  // Kf+Vf dead by then (16 MB)

  dim3 blk(256, 1, 1);
  const long long M1 = 1024 * 1024;

  // Selection-path projections (fp64 acc, unchanged)
  gemm_k<float, double, true, 1, false><<<dim3(16, 32, 1), blk, 0, stream>>>(
      x, Wq, bq, Q, 1024, 1024, 1024, 1024, 0, 0, 0, 0);
  gemm_k<float, double, true, 1, false><<<dim3(16, 32, 1), blk, 0, stream>>>(
      x, Wk, bk, Kf, 1024, 1024, 1024, 1024, 0, 0, 0, 0);
  // Value-path V projection: MFMA split-bf16
  mfma_gemm_k<true, 1><<<dim3(8, 16, 1), blk, 0, stream>>>(
      x, Wv, bv, Vf, 1024, 1024, 1024, 1024, 0, 0);

  // Compress: Kc (fp64, unchanged), Vc (MFMA split-bf16)
  gemm_k<float, double, false, 2, false><<<dim3(16, 16, 2), blk, 0, stream>>>(
      Wc, Kf, bc, Kc, 1024, 1024, 1024, 1024, 0, M1, M1, 0);
  mfma_gemm_k<false, 2><<<dim3(8, 8, 2), blk, 0, stream>>>(
      Wc, Vf, bc, Vc, 1024, 1024, 1024, 1024, M1, M1);

  kn_k2<<<dim3(128), dim3(256), 0, stream>>>(Kc, kn);

  for (int gb = 0; gb < 32; gb += G) {
    gemm_k<double, double, true, 0, true><<<dim3(16, 16, G), blk, 0, stream>>>(
        Q, Kc, nullptr, dotp, 64, 1024, 1024, 1024, 0, 0, 0, gb);
    topk_attn_k<<<dim3(256 * G), blk, 0, stream>>>(dotp, kn, Vc, at, gb);
  }

  // Output projection: MFMA split-bf16
  mfma_gemm_k<true, 1><<<dim3(8, 16, 1), blk, 0, stream>>>(
      at, Wo, bo, out, 1024, 1024, 1024, 1024, 0, 0);
}

// Round 9
// 962.157 us; speedup vs baseline: 1.1178x; 1.1178x over previous
//
#include <hip/hip_runtime.h>
#include <type_traits>

// ---------------------------------------------------------------------------
// CSAAttention — round 9 (bisect): round-5 validated selection path
// (scalar fp64 gemm_k for Q/K/Kc, SIM variant for dots, radix top-64)
// + ONLY the retiled 64x64 bf16-split MFMA value path (V, Vc, Wo) from R8.
// Selection-path numerics are bit-identical to rounds 4/5/7 (fp64 FMA chain,
// same k order) — absmax must be exactly 0.00390625 if the retile is correct.
// ---------------------------------------------------------------------------

#define DEVI __device__ __forceinline__

constexpr int Tn = 1024;
constexpr int Cn = 1024;
constexpr int Hn = 16;

typedef short bf16x8 __attribute__((ext_vector_type(8)));
typedef float f32x4 __attribute__((ext_vector_type(4)));

DEVI int wsumi(int v)   { for (int m = 1; m < 64; m <<= 1) v += __shfl_xor(v, m); return v; }
DEVI int wmini(int v)   { for (int m = 1; m < 64; m <<= 1) { int o = __shfl_xor(v, m); v = o < v ? o : v; } return v; }
DEVI float wfmax(float v){ for (int m = 1; m < 64; m <<= 1) v = fmaxf(v, __shfl_xor(v, m)); return v; }
DEVI float wfsum(float v){ for (int m = 1; m < 64; m <<= 1) v += __shfl_xor(v, m); return v; }

DEVI unsigned long long mapd(double x) {  // monotone fp64 -> uint64
  unsigned long long b = (unsigned long long)__double_as_longlong(x);
  return (b >> 63) ? ~b : (b | 0x8000000000000000ull);
}

DEVI unsigned short f2bf_rne(float x) {
  unsigned u = __float_as_uint(x);
  u += 0x7fffu + ((u >> 16) & 1u);
  return (unsigned short)(u >> 16);
}
struct BfPair { short hi, lo; };
DEVI BfPair split2(float x) {
  unsigned short h = f2bf_rne(x);
  float hf = __uint_as_float(((unsigned)h) << 16);
  BfPair r;
  r.hi = (short)h;
  r.lo = (short)f2bf_rne(x - hf);
  return r;
}

// ---------------------------------------------------------------------------
// Selection-path tiled GEMM (validated rounds 4-7; numerics frozen).
// ---------------------------------------------------------------------------
template <typename OUTT, typename ACCT, bool BTRANS, int BIASMODE, bool SIM>
__global__ __launch_bounds__(256) void gemm_k(
    const float* __restrict__ A, const float* __restrict__ B,
    const float* __restrict__ bias, OUTT* __restrict__ C,
    int Kd, int lda, int ldb, int ldc,
    long long zA, long long zB, long long zC, int group_base)
{
  __shared__ float As[16][68];
  __shared__ float Bs[16][68];

  size_t offA, offB, offC;
  if (SIM) {
    int pair = group_base + (int)blockIdx.z;
    int bb = pair >> 4, hh = pair & 15;
    offA = ((size_t)bb * Tn) * (size_t)lda + (size_t)hh * 64;
    offB = ((size_t)bb * Cn) * (size_t)ldb + (size_t)hh * 64;
    offC = (size_t)blockIdx.z * (size_t)Tn * (size_t)ldc;
  } else {
    offA = (size_t)blockIdx.z * (size_t)zA;
    offB = (size_t)blockIdx.z * (size_t)zB;
    offC = (size_t)blockIdx.z * (size_t)zC;
  }
  const float* Ab = A + offA;
  const float* Bb = B + offB;
  OUTT* Cb = C + offC;

  const int tid = threadIdx.x;
  const int tx = tid & 15, ty = tid >> 4;
  const int m0 = blockIdx.y * 64, n0 = blockIdx.x * 64;

  ACCT acc[4][4];
#pragma unroll
  for (int i = 0; i < 4; ++i)
#pragma unroll
    for (int j = 0; j < 4; ++j) acc[i][j] = (ACCT)0;

  for (int k0 = 0; k0 < Kd; k0 += 16) {
    {
      int m = tid >> 2, kf = tid & 3;
      float4 a = *(const float4*)(Ab + (size_t)(m0 + m) * lda + k0 + 4 * kf);
      As[4 * kf + 0][m] = a.x; As[4 * kf + 1][m] = a.y;
      As[4 * kf + 2][m] = a.z; As[4 * kf + 3][m] = a.w;
    }
    if (BTRANS) {
      int n = tid >> 2, kf = tid & 3;
      float4 b = *(const float4*)(Bb + (size_t)(n0 + n) * ldb + k0 + 4 * kf);
      Bs[4 * kf + 0][n] = b.x; Bs[4 * kf + 1][n] = b.y;
      Bs[4 * kf + 2][n] = b.z; Bs[4 * kf + 3][n] = b.w;
    } else {
      int k = tid >> 4, nf = tid & 15;
      float4 b = *(const float4*)(Bb + (size_t)(k0 + k) * ldb + n0 + 4 * nf);
      *(float4*)&Bs[k][4 * nf] = b;
    }
    __syncthreads();
#pragma unroll
    for (int k = 0; k < 16; ++k) {
      float4 a4 = *(const float4*)&As[k][4 * ty];
      float4 b4 = *(const float4*)&Bs[k][4 * tx];
      float av[4] = {a4.x, a4.y, a4.z, a4.w};
      float bv[4] = {b4.x, b4.y, b4.z, b4.w};
#pragma unroll
      for (int i = 0; i < 4; ++i)
#pragma unroll
        for (int j = 0; j < 4; ++j)
          acc[i][j] += (ACCT)av[i] * (ACCT)bv[j];
    }
    __syncthreads();
  }

  if constexpr (std::is_same<OUTT, double>::value) {
#pragma unroll
    for (int i = 0; i < 4; ++i) {
      size_t m = (size_t)(m0 + 4 * ty + i);
      double* p = (double*)Cb + m * ldc + n0 + 4 * tx;
      p[0] = (double)acc[i][0]; p[1] = (double)acc[i][1];
      p[2] = (double)acc[i][2]; p[3] = (double)acc[i][3];
    }
  } else {
    float cbv[4] = {0.f, 0.f, 0.f, 0.f};
    if (BIASMODE == 1) {
      float4 b4 = *(const float4*)(bias + n0 + 4 * tx);
      cbv[0] = b4.x; cbv[1] = b4.y; cbv[2] = b4.z; cbv[3] = b4.w;
    }
#pragma unroll
    for (int i = 0; i < 4; ++i) {
      int m = m0 + 4 * ty + i;
      float rb = (BIASMODE == 2) ? bias[m] : 0.f;
      float4 s;
      s.x = (float)acc[i][0] + cbv[0] + rb;
      s.y = (float)acc[i][1] + cbv[1] + rb;
      s.z = (float)acc[i][2] + cbv[2] + rb;
      s.w = (float)acc[i][3] + cbv[3] + rb;
      *(float4*)((float*)Cb + (size_t)m * ldc + n0 + 4 * tx) = s;
    }
  }
}

// ---------------------------------------------------------------------------
// Value-path bf16 split MFMA GEMM (3 passes), 64x64 tile / BK=32 / 4 waves
// (wave 32x32, 2x2 fragments). UNDER TEST this round.
// ---------------------------------------------------------------------------
template <bool BTRANS, int BIASMODE>
__global__ __launch_bounds__(256) void mfma_gemm_k(
    const float* __restrict__ A, const float* __restrict__ B,
    const float* __restrict__ bias, float* __restrict__ C,
    int Kd, int lda, int ldb, int ldc, long long zB, long long zC)
{
  __shared__ short Ah[4 * 64 * 8];   // [kg][row][8] 16B blocks
  __shared__ short Al[4 * 64 * 8];
  __shared__ short Bh[4 * 64 * 8];
  __shared__ short Bl[4 * 64 * 8];

  const float* Bz = B + (size_t)blockIdx.z * (size_t)zB;
  float* Cz = C + (size_t)blockIdx.z * (size_t)zC;

  const int tid = threadIdx.x;
  const int lane = tid & 63, w = tid >> 6;
  const int wr = w >> 1, wc = w & 1;
  const int m0 = blockIdx.y * 64, n0 = blockIdx.x * 64;
  const int r16 = lane & 15, kg = lane >> 4;

  f32x4 acc[2][2];
#pragma unroll
  for (int i = 0; i < 2; ++i)
#pragma unroll
    for (int j = 0; j < 2; ++j) acc[i][j] = (f32x4){0.f, 0.f, 0.f, 0.f};

  for (int k0 = 0; k0 < Kd; k0 += 32) {
    {  // stage A: row = tid>>2, 8 consecutive k
      int row = tid >> 2, kseg = tid & 3;
      const float* p = A + (size_t)(m0 + row) * lda + k0 + kseg * 8;
      float4 v0 = *(const float4*)p;
      float4 v1 = *(const float4*)(p + 4);
      BfPair q0 = split2(v0.x), q1 = split2(v0.y), q2 = split2(v0.z), q3 = split2(v0.w);
      BfPair q4 = split2(v1.x), q5 = split2(v1.y), q6 = split2(v1.z), q7 = split2(v1.w);
      bf16x8 h = {q0.hi, q1.hi, q2.hi, q3.hi, q4.hi, q5.hi, q6.hi, q7.hi};
      bf16x8 l = {q0.lo, q1.lo, q2.lo, q3.lo, q4.lo, q5.lo, q6.lo, q7.lo};
      int idx = (kseg * 64 + row) * 8;
      *(bf16x8*)&Ah[idx] = h;
      *(bf16x8*)&Al[idx] = l;
    }
    if (BTRANS) {  // B rows are n
      int row = tid >> 2, kseg = tid & 3;
      const float* p = Bz + (size_t)(n0 + row) * ldb + k0 + kseg * 8;
      float4 v0 = *(const float4*)p;
      float4 v1 = *(const float4*)(p + 4);
      BfPair q0 = split2(v0.x), q1 = split2(v0.y), q2 = split2(v0.z), q3 = split2(v0.w);
      BfPair q4 = split2(v1.x), q5 = split2(v1.y), q6 = split2(v1.z), q7 = split2(v1.w);
      bf16x8 h = {q0.hi, q1.hi, q2.hi, q3.hi, q4.hi, q5.hi, q6.hi, q7.hi};
      bf16x8 l = {q0.lo, q1.lo, q2.lo, q3.lo, q4.lo, q5.lo, q6.lo, q7.lo};
      int idx = (kseg * 64 + row) * 8;
      *(bf16x8*)&Bh[idx] = h;
      *(bf16x8*)&Bl[idx] = l;
    } else {       // B[k][n]: column gather, 8 consecutive k per thread
      int col = tid & 63, kseg = tid >> 6;
      short hv[8], lv[8];
#pragma unroll
      for (int j = 0; j < 8; ++j) {
        BfPair p = split2(Bz[(size_t)(k0 + kseg * 8 + j) * ldb + n0 + col]);
        hv[j] = p.hi; lv[j] = p.lo;
      }
      bf16x8 h = {hv[0], hv[1], hv[2], hv[3], hv[4], hv[5], hv[6], hv[7]};
      bf16x8 l = {lv[0], lv[1], lv[2], lv[3], lv[4], lv[5], lv[6], lv[7]};
      int idx = (kseg * 64 + col) * 8;
      *(bf16x8*)&Bh[idx] = h;
      *(bf16x8*)&Bl[idx] = l;
    }
    __syncthreads();

    bf16x8 ah[2], al[2], bh[2], bl[2];
#pragma unroll
    for (int f = 0; f < 2; ++f) {
      int ia = (kg * 64 + wr * 32 + f * 16 + r16) * 8;
      int ib = (kg * 64 + wc * 32 + f * 16 + r16) * 8;
      ah[f] = *(const bf16x8*)&Ah[ia];
      al[f] = *(const bf16x8*)&Al[ia];
      bh[f] = *(const bf16x8*)&Bh[ib];
      bl[f] = *(const bf16x8*)&Bl[ib];
    }
#pragma unroll
    for (int fr = 0; fr < 2; ++fr)
#pragma unroll
      for (int fc = 0; fc < 2; ++fc) {
        f32x4 c = acc[fr][fc];
        c = __builtin_amdgcn_mfma_f32_16x16x32_bf16(al[fr], bh[fc], c, 0, 0, 0);
        c = __builtin_amdgcn_mfma_f32_16x16x32_bf16(ah[fr], bl[fc], c, 0, 0, 0);
        c = __builtin_amdgcn_mfma_f32_16x16x32_bf16(ah[fr], bh[fc], c, 0, 0, 0);
        acc[fr][fc] = c;
      }
    __syncthreads();
  }

#pragma unroll
  for (int fr = 0; fr < 2; ++fr)
#pragma unroll
    for (int fc = 0; fc < 2; ++fc) {
      int col = n0 + wc * 32 + fc * 16 + r16;
      float cb = (BIASMODE == 1) ? bias[col] : 0.f;
#pragma unroll
      for (int rr = 0; rr < 4; ++rr) {
        int row = m0 + wr * 32 + fr * 16 + kg * 4 + rr;
        float rb = (BIASMODE == 2) ? bias[row] : 0.f;
        Cz[(size_t)row * ldc + col] = acc[fr][fc][rr] + cb + rb;
      }
    }
}

// kn[b*16+h][c] = 1 / max(||Kc[b, c, h*64 : +64]||, 1e-12)   (fp64)
__global__ __launch_bounds__(256) void kn_k2(const float* __restrict__ Kc,
                                             double* __restrict__ kn)
{
  int idx = (int)blockIdx.x * 256 + (int)threadIdx.x;  // [0, 32768)
  int c = idx & 1023;
  int p = idx >> 10;
  int b = p >> 4, h = p & 15;
  const float* row = Kc + ((size_t)(b * 1024 + c)) * 1024 + h * 64;
  double s = 0.0;
  for (int d = 0; d < 64; ++d) { double v = (double)row[d]; s += v * v; }
  kn[(size_t)p * 1024 + c] = 1.0 / fmax(sqrt(s), 1e-12);
}

// Fused exact top-64 + softmax + PV (validated; unchanged).
__global__ __launch_bounds__(256) void topk_attn_k(
    const double* __restrict__ dotb, const double* __restrict__ kn,
    const float* __restrict__ Vc, float* __restrict__ attnout, int group_base)
{
  __shared__ int sC[4][64];
  __shared__ float sD[4][64];

  const int lane = threadIdx.x & 63, wv = threadIdx.x >> 6;
  const int g = (int)blockIdx.x >> 8;
  const int t = ((int)blockIdx.x & 255) * 4 + wv;
  const int pair = group_base + g;
  const int bb = pair >> 4, hh = pair & 15;

  const double* drow = dotb + ((size_t)g * Tn + t) * (size_t)Cn;
  const double* knr  = kn + ((size_t)(bb * Hn + hh)) * Cn;

  double dv[16];
  unsigned long long u[16];
#pragma unroll
  for (int j = 0; j < 8; ++j) {
    double2 dd = *(const double2*)(drow + j * 128 + 2 * lane);
    double2 kk = *(const double2*)(knr  + j * 128 + 2 * lane);
    dv[2 * j] = dd.x; dv[2 * j + 1] = dd.y;
    u[2 * j]     = mapd(dd.x * kk.x);
    u[2 * j + 1] = mapd(dd.y * kk.y);
  }
  unsigned hi[16];
#pragma unroll
  for (int i = 0; i < 16; ++i) hi[i] = (unsigned)(u[i] >> 32);

  unsigned TH = 0;
  for (int bit = 31; bit >= 0; --bit) {
    unsigned Tc = TH | (1u << bit);
    int c = 0;
#pragma unroll
    for (int i = 0; i < 16; ++i) c += (hi[i] >= Tc);
    if (wsumi(c) >= 64) TH = Tc;
  }
  int mhi = 0;
#pragma unroll
  for (int i = 0; i < 16; ++i) mhi += (hi[i] > TH);
  mhi = wsumi(mhi);
  const int need1 = 64 - mhi;
  unsigned TL = 0;
  for (int bit = 31; bit >= 0; --bit) {
    unsigned Tc = TL | (1u << bit);
    int c = 0;
#pragma unroll
    for (int i = 0; i < 16; ++i) c += (hi[i] == TH && (unsigned)u[i] >= Tc);
    if (wsumi(c) >= need1) TL = Tc;
  }
  const unsigned long long V64 = ((unsigned long long)TH << 32) | TL;

  int base = 0;
#pragma unroll
  for (int i = 0; i < 16; ++i) {
    const int cix = 128 * (i >> 1) + 2 * lane + (i & 1);
    bool sel = (u[i] > V64);
    unsigned long long mk = __ballot(sel);
    if (sel) {
      int r = __popcll(mk & ((1ull << lane) - 1ull));
      sC[wv][base + r] = cix;
      sD[wv][base + r] = (float)dv[i];
    }
    base += __popcll(mk);
  }
  const int need = 64 - base;
  unsigned taken = 0;
  for (int r = 0; r < need; ++r) {
    int mn = 0x7fffffff;
#pragma unroll
    for (int i = 0; i < 16; ++i) {
      int cix = 128 * (i >> 1) + 2 * lane + (i & 1);
      if (u[i] == V64 && !((taken >> i) & 1u)) mn = mn < cix ? mn : cix;
    }
    mn = wmini(mn);
#pragma unroll
    for (int i = 0; i < 16; ++i) {
      int cix = 128 * (i >> 1) + 2 * lane + (i & 1);
      if (u[i] == V64 && !((taken >> i) & 1u) && cix == mn) {
        taken |= 1u << i;
        sC[wv][base + r] = mn;
        sD[wv][base + r] = (float)dv[i];
      }
    }
  }
  __syncthreads();

  int ck = sC[wv][lane];
  float sc = sD[wv][lane] * 0.125f;
  float mx = wfmax(sc);
  float w = expf(sc - mx);
  float sw = wfsum(w);
  w /= sw;

  const float* Vb = Vc + (size_t)bb * ((size_t)Cn * 1024) + hh * 64 + lane;
  float acc = 0.f;
#pragma unroll 4
  for (int k = 0; k < 64; ++k) {
    int c = __shfl(ck, k);
    float wk = __shfl(w, k);
    acc = fmaf(wk, Vb[(size_t)c * 1024], acc);
  }
  attnout[((size_t)(bb * Tn + t)) * 1024 + hh * 64 + lane] = acc;
}

// ---------------------------------------------------------------------------
extern "C" void kernel_launch(void* const* d_in, const int* in_sizes, int n_in,
                              void* d_out, int out_size, void* d_ws, size_t ws_size,
                              hipStream_t stream)
{
  const float* x  = (const float*)d_in[0];
  const float* Wq = (const float*)d_in[1];
  const float* bq = (const float*)d_in[2];
  const float* Wk = (const float*)d_in[3];
  const float* bk = (const float*)d_in[4];
  const float* Wv = (const float*)d_in[5];
  const float* bv = (const float*)d_in[6];
  const float* Wo = (const float*)d_in[7];
  const float* bo = (const float*)d_in[8];
  const float* Wc = (const float*)d_in[9];
  const float* bc = (const float*)d_in[10];
  float* out = (float*)d_out;

  const size_t NE = (size_t)2048 * 1024;
  float* Q  = (float*)d_ws;
  float* Kf = Q + NE;
  float* Vf = Kf + NE;
  float* Kc = Vf + NE;
  float* Vc = Kc + NE;
  float* at = Vc + NE;
  double* kn = (double*)(at + NE);
  double* tail = kn + 32768;

  const size_t fixedB = 6 * NE * 4 + 32768 * 8;
  const size_t dotPairB = (size_t)Tn * Cn * 8;  // 8 MB per (b,h) pair
  if (ws_size < fixedB) return;

  size_t rem = ws_size - fixedB;
  double* dotp; int G;
  if      (rem >= 8 * dotPairB) { G = 8; dotp = tail; }
  else if (rem >= 4 * dotPairB) { G = 4; dotp = tail; }
  else if (rem >= 2 * dotPairB) { G = 2; dotp = tail; }
  else { G = 2; dotp = (double*)Kf; }  // Kf+Vf dead by then (16 MB)

  dim3 blk(256, 1, 1);
  const long long M1 = 1024 * 1024;

  // Selection-path projections (scalar fp64 acc — validated, frozen)
  gemm_k<float, double, true, 1, false><<<dim3(16, 32, 1), blk, 0, stream>>>(
      x, Wq, bq, Q, 1024, 1024, 1024, 1024, 0, 0, 0, 0);
  gemm_k<float, double, true, 1, false><<<dim3(16, 32, 1), blk, 0, stream>>>(
      x, Wk, bk, Kf, 1024, 1024, 1024, 1024, 0, 0, 0, 0);
  // Value-path V projection: retiled bf16 split MFMA (under test)
  mfma_gemm_k<true, 1><<<dim3(16, 32, 1), blk, 0, stream>>>(
      x, Wv, bv, Vf, 1024, 1024, 1024, 1024, 0, 0);

  // Compress: Kc scalar fp64 (validated), Vc retiled bf16 MFMA (under test)
  gemm_k<float, double, false, 2, false><<<dim3(16, 16, 2), blk, 0, stream>>>(
      Wc, Kf, bc, Kc, 1024, 1024, 1024, 1024, 0, M1, M1, 0);
  mfma_gemm_k<false, 2><<<dim3(16, 16, 2), blk, 0, stream>>>(
      Wc, Vf, bc, Vc, 1024, 1024, 1024, 1024, M1, M1);

  kn_k2<<<dim3(128), dim3(256), 0, stream>>>(Kc, kn);

  // Per (b,h) group: fp64 dot plane (validated SIM path), then topk+PV
  for (int gb = 0; gb < 32; gb += G) {
    gemm_k<double, double, true, 0, true><<<dim3(16, 16, G), blk, 0, stream>>>(
        Q, Kc, nullptr, dotp, 64, 1024, 1024, 1024, 0, 0, 0, gb);
    topk_attn_k<<<dim3(256 * G), blk, 0, stream>>>(dotp, kn, Vc, at, gb);
  }

  // Output projection: retiled bf16 split MFMA (under test)
  mfma_gemm_k<true, 1><<<dim3(16, 32, 1), blk, 0, stream>>>(
      at, Wo, bo, out, 1024, 1024, 1024, 1024, 0, 0);
}